// Round 9
// baseline (457.983 us; speedup 1.0000x reference)
//
#include <hip/hip_runtime.h>
#include <hip/hip_bf16.h>

#define D 128

typedef __bf16 bf16x8 __attribute__((ext_vector_type(8)));
typedef float floatx4 __attribute__((ext_vector_type(4)));

// ---------------- CSR build ----------------

__global__ void k_count(const int* __restrict__ dst, int E, int* __restrict__ cnt) {
    int e = blockIdx.x * blockDim.x + threadIdx.x;
    if (e < E) atomicAdd(&cnt[dst[e]], 1);
}

__global__ __launch_bounds__(256) void k_scan1(const int* __restrict__ cnt, int n,
                                               int* __restrict__ bsum) {
    int i = blockIdx.x * 256 + threadIdx.x;
    int x = (i < n) ? cnt[i] : 0;
    #pragma unroll
    for (int off = 32; off > 0; off >>= 1) x += __shfl_xor(x, off, 64);
    __shared__ int ws[4];
    if ((threadIdx.x & 63) == 0) ws[threadIdx.x >> 6] = x;
    __syncthreads();
    if (threadIdx.x == 0) bsum[blockIdx.x] = ws[0] + ws[1] + ws[2] + ws[3];
}

__global__ void k_scan2(const int* __restrict__ bsum, int nb, int* __restrict__ boff) {
    int t = threadIdx.x;
    int lane = t & 63, wid = t >> 6;
    int x = (t < nb) ? bsum[t] : 0;
    int incl = x;
    #pragma unroll
    for (int off = 1; off < 64; off <<= 1) {
        int y = __shfl_up(incl, off, 64);
        if (lane >= off) incl += y;
    }
    __shared__ int ws[4];
    if (lane == 63) ws[wid] = incl;
    __syncthreads();
    int o = 0;
    for (int w = 0; w < wid; w++) o += ws[w];
    if (t < nb) boff[t] = o + incl - x;
}

__global__ __launch_bounds__(256) void k_scan3(const int* __restrict__ cnt,
                                               const int* __restrict__ boff, int n, int E,
                                               int* __restrict__ row_ptr, int* __restrict__ cursor,
                                               float* __restrict__ dinv) {
    int t = threadIdx.x;
    int lane = t & 63, wid = t >> 6;
    int i = blockIdx.x * 256 + t;
    int x = (i < n) ? cnt[i] : 0;
    int incl = x;
    #pragma unroll
    for (int off = 1; off < 64; off <<= 1) {
        int y = __shfl_up(incl, off, 64);
        if (lane >= off) incl += y;
    }
    __shared__ int ws[4];
    if (lane == 63) ws[wid] = incl;
    __syncthreads();
    int o = boff[blockIdx.x];
    for (int w = 0; w < wid; w++) o += ws[w];
    if (i < n) {
        int excl = o + incl - x;
        row_ptr[i] = excl;
        cursor[i] = excl;
        dinv[i] = rsqrtf((float)(x + 1));  // +1 self loop
    }
    if (blockIdx.x == 0 && t == 0) row_ptr[n] = E;
}

// Range-partitioned fill (round-8 proven): blockIdx.y = dst-range (8 ranges).
__global__ __launch_bounds__(256) void k_fill(const int* __restrict__ src,
                                              const int* __restrict__ dst, int E,
                                              int* __restrict__ cursor,
                                              unsigned short* __restrict__ esrc, int n) {
    int rs = (n + 7) >> 3;
    int lo = blockIdx.y * rs, hi = lo + rs;
    int step = gridDim.x * 256;
    for (int e = blockIdx.x * 256 + threadIdx.x; e < E; e += step) {
        int d = dst[e];
        int s = src[e];
        if (d >= lo && d < hi) {
            int p = atomicAdd(&cursor[d], 1);
            esrc[p] = (unsigned short)s;
        }
    }
}

// ---------------- W transpose+bf16 precompute: Wt[n][k] = bf16(W[k][n]) ----------------

__global__ __launch_bounds__(256) void k_prepw(const float* __restrict__ W1,
                                               const float* __restrict__ W2,
                                               const float* __restrict__ W3,
                                               unsigned short* __restrict__ Wt) {
    const float* W = (blockIdx.x == 0) ? W1 : (blockIdx.x == 1) ? W2 : W3;
    unsigned short* o = Wt + blockIdx.x * 16384;
    for (int i = threadIdx.x; i < 16384; i += 256) {
        int k = i >> 7, nn = i & 127;
        __hip_bfloat16 h = __float2bfloat16(W[i]);
        o[nn * 128 + k] = *(unsigned short*)&h;
    }
}

// ---------------- MFMA GEMM (round-8 proven) ----------

__global__ __launch_bounds__(256) void k_gemm(
    const float* __restrict__ X, const unsigned short* __restrict__ Wt,
    const float* __restrict__ scale, const float* __restrict__ stats_in,
    const float* __restrict__ gamma, const float* __restrict__ beta,
    float* __restrict__ stats_zero,
    unsigned short* __restrict__ hs, int n, float invN) {
    __shared__ unsigned short Wl[128 * 128];
    __shared__ float bnl[256];
    int t = threadIdx.x;
    if (stats_in && t < 128) {
        float s = stats_in[t] + stats_in[256 + t] + stats_in[512 + t] + stats_in[768 + t];
        float q = stats_in[128 + t] + stats_in[384 + t] + stats_in[640 + t] + stats_in[896 + t];
        float mean = s * invN;
        float var = q * invN - mean * mean;
        float a = gamma[t] * rsqrtf(var + 1e-5f);
        bnl[t] = a;
        bnl[128 + t] = beta[t] - mean * a;
    }
    if (stats_zero && blockIdx.x == 0) {
        stats_zero[t] = 0.f;
        stats_zero[256 + t] = 0.f;
        stats_zero[512 + t] = 0.f;
        stats_zero[768 + t] = 0.f;
    }
    {
        const uint4* wg = (const uint4*)Wt;
        uint4* wl4 = (uint4*)Wl;
        #pragma unroll
        for (int j = 0; j < 8; j++) {
            int idx = j * 256 + t;
            int nn = idx >> 4, lc = idx & 15;
            wl4[nn * 16 + (lc ^ (nn & 15))] = wg[idx];
        }
    }
    __syncthreads();

    int l = t & 63, w = t >> 6;
    int lm = l & 15, quad = l >> 4;
    int m = blockIdx.x * 64 + w * 16 + lm;
    int rm = (m < n) ? m : (n - 1);
    const float* xrow = X + (size_t)rm * D;

    floatx4 acc[8];
    #pragma unroll
    for (int nt = 0; nt < 8; nt++) acc[nt] = (floatx4){0.f, 0.f, 0.f, 0.f};

    #pragma unroll
    for (int ks = 0; ks < 4; ks++) {
        int k0 = ks * 32 + quad * 8;
        float4 xa = *(const float4*)(xrow + k0);
        float4 xb = *(const float4*)(xrow + k0 + 4);
        if (stats_in) {
            float4 a0 = *(const float4*)&bnl[k0];
            float4 a1 = *(const float4*)&bnl[k0 + 4];
            float4 c0 = *(const float4*)&bnl[128 + k0];
            float4 c1 = *(const float4*)&bnl[128 + k0 + 4];
            xa.x = fmaxf(xa.x * a0.x + c0.x, 0.f);
            xa.y = fmaxf(xa.y * a0.y + c0.y, 0.f);
            xa.z = fmaxf(xa.z * a0.z + c0.z, 0.f);
            xa.w = fmaxf(xa.w * a0.w + c0.w, 0.f);
            xb.x = fmaxf(xb.x * a1.x + c1.x, 0.f);
            xb.y = fmaxf(xb.y * a1.y + c1.y, 0.f);
            xb.z = fmaxf(xb.z * a1.z + c1.z, 0.f);
            xb.w = fmaxf(xb.w * a1.w + c1.w, 0.f);
        }
        bf16x8 xf;
        xf[0] = (__bf16)xa.x; xf[1] = (__bf16)xa.y;
        xf[2] = (__bf16)xa.z; xf[3] = (__bf16)xa.w;
        xf[4] = (__bf16)xb.x; xf[5] = (__bf16)xb.y;
        xf[6] = (__bf16)xb.z; xf[7] = (__bf16)xb.w;
        int pc = (ks * 4 + quad) ^ lm;
        #pragma unroll
        for (int nt = 0; nt < 8; nt++) {
            const bf16x8 wf = *(const bf16x8*)&Wl[(nt * 16 + lm) * 128 + pc * 8];
            acc[nt] = __builtin_amdgcn_mfma_f32_16x16x32_bf16(wf, xf, acc[nt], 0, 0, 0);
        }
    }

    float s = scale[rm];
    if (m < n) {
        #pragma unroll
        for (int nt = 0; nt < 8; nt++) {
            __hip_bfloat16 h0 = __float2bfloat16(acc[nt][0] * s);
            __hip_bfloat16 h1 = __float2bfloat16(acc[nt][1] * s);
            __hip_bfloat16 h2 = __float2bfloat16(acc[nt][2] * s);
            __hip_bfloat16 h3 = __float2bfloat16(acc[nt][3] * s);
            uint2 uu;
            uu.x = (unsigned)*(unsigned short*)&h0 | ((unsigned)*(unsigned short*)&h1 << 16);
            uu.y = (unsigned)*(unsigned short*)&h2 | ((unsigned)*(unsigned short*)&h3 << 16);
            *(uint2*)&hs[(size_t)m * D + nt * 16 + quad * 4] = uu;
        }
    }
}

// ---------------- Column-blocked aggregation (round-7 parallel shape) ----------
// One node per 16-lane group, 16 nodes/block, 3125 blocks x 4 passes.
// mode 0: fused BN-stats (per-block LDS reduce -> 4-way-split global atomics).

__device__ inline float2 bf2f(unsigned u) {
    union { unsigned i; float f; } lo, hi;
    lo.i = u << 16;
    hi.i = u & 0xffff0000u;
    float2 r; r.x = lo.f; r.y = hi.f; return r;
}

__global__ __launch_bounds__(256) void k_agg(
    const unsigned* __restrict__ hs, const int* __restrict__ row_ptr,
    const unsigned short* __restrict__ esrc, const float* __restrict__ dinv,
    const float* __restrict__ bias, float* __restrict__ out,
    float* __restrict__ stats4, int n, int mode) {
    __shared__ float ls0[256], ls1[256], lq0[256], lq1[256];
    int t = threadIdx.x;
    int grp = t >> 4, sub = t & 15;
    int p = blockIdx.y;
    int col32 = p * 16 + sub;
    int node = blockIdx.x * 16 + grp;
    bool valid = node < n;
    int nd = valid ? node : (n - 1);

    int beg = row_ptr[nd], end = row_ptr[nd + 1];
    float2 acc = bf2f(hs[(size_t)nd * 64 + col32]);   // self loop
    for (int base = beg; base < end; base += 16) {
        int m = end - base;
        if (m > 16) m = 16;
        int eid = (base + sub < end) ? (int)esrc[base + sub] : 0;
        int i = 0;
        for (; i + 8 <= m; i += 8) {
            int u0 = __shfl(eid, i + 0, 16);
            int u1 = __shfl(eid, i + 1, 16);
            int u2 = __shfl(eid, i + 2, 16);
            int u3 = __shfl(eid, i + 3, 16);
            int u4 = __shfl(eid, i + 4, 16);
            int u5 = __shfl(eid, i + 5, 16);
            int u6 = __shfl(eid, i + 6, 16);
            int u7 = __shfl(eid, i + 7, 16);
            unsigned p0 = hs[(size_t)u0 * 64 + col32];
            unsigned p1 = hs[(size_t)u1 * 64 + col32];
            unsigned p2 = hs[(size_t)u2 * 64 + col32];
            unsigned p3 = hs[(size_t)u3 * 64 + col32];
            unsigned p4 = hs[(size_t)u4 * 64 + col32];
            unsigned p5 = hs[(size_t)u5 * 64 + col32];
            unsigned p6 = hs[(size_t)u6 * 64 + col32];
            unsigned p7 = hs[(size_t)u7 * 64 + col32];
            float2 v0 = bf2f(p0), v1 = bf2f(p1), v2 = bf2f(p2), v3 = bf2f(p3);
            float2 v4 = bf2f(p4), v5 = bf2f(p5), v6 = bf2f(p6), v7 = bf2f(p7);
            acc.x += ((v0.x + v1.x) + (v2.x + v3.x)) + ((v4.x + v5.x) + (v6.x + v7.x));
            acc.y += ((v0.y + v1.y) + (v2.y + v3.y)) + ((v4.y + v5.y) + (v6.y + v7.y));
        }
        for (; i + 4 <= m; i += 4) {
            int u0 = __shfl(eid, i + 0, 16);
            int u1 = __shfl(eid, i + 1, 16);
            int u2 = __shfl(eid, i + 2, 16);
            int u3 = __shfl(eid, i + 3, 16);
            unsigned p0 = hs[(size_t)u0 * 64 + col32];
            unsigned p1 = hs[(size_t)u1 * 64 + col32];
            unsigned p2 = hs[(size_t)u2 * 64 + col32];
            unsigned p3 = hs[(size_t)u3 * 64 + col32];
            float2 v0 = bf2f(p0), v1 = bf2f(p1), v2 = bf2f(p2), v3 = bf2f(p3);
            acc.x += (v0.x + v1.x) + (v2.x + v3.x);
            acc.y += (v0.y + v1.y) + (v2.y + v3.y);
        }
        for (; i < m; i++) {
            int u = __shfl(eid, i, 16);
            float2 v = bf2f(hs[(size_t)u * 64 + col32]);
            acc.x += v.x;
            acc.y += v.y;
        }
    }
    float sc = dinv[nd];
    float2 b = *(const float2*)&bias[col32 * 2];
    float2 r;
    r.x = acc.x * sc + b.x;
    r.y = acc.y * sc + b.y;
    if (valid) *(float2*)&out[(size_t)node * D + col32 * 2] = r;

    if (mode == 0) {
        float m0 = valid ? r.x : 0.f;
        float m1 = valid ? r.y : 0.f;
        ls0[t] = m0; ls1[t] = m1;
        lq0[t] = m0 * m0; lq1[t] = m1 * m1;
        __syncthreads();
        if (t < 16) {
            float a0 = 0.f, a1 = 0.f, c0 = 0.f, c1 = 0.f;
            #pragma unroll
            for (int g = 0; g < 16; g++) {
                int i = g * 16 + t;
                a0 += ls0[i]; a1 += ls1[i];
                c0 += lq0[i]; c1 += lq1[i];
            }
            float* sbuf = stats4 + (blockIdx.x & 3) * 256;
            atomicAdd(&sbuf[p * 32 + 2 * t], a0);
            atomicAdd(&sbuf[p * 32 + 2 * t + 1], a1);
            atomicAdd(&sbuf[128 + p * 32 + 2 * t], c0);
            atomicAdd(&sbuf[128 + p * 32 + 2 * t + 1], c1);
        }
    }
}

// ---------------- row L2 normalize ----------------

__global__ __launch_bounds__(256) void k_l2norm(const float* __restrict__ h,
                                                float* __restrict__ out, int n) {
    int node = blockIdx.x * 4 + (threadIdx.x >> 6);
    if (node >= n) return;
    int lane = threadIdx.x & 63;
    float2 v = *(const float2*)&h[(size_t)node * D + lane * 2];
    float pw = v.x * v.x + v.y * v.y;
    #pragma unroll
    for (int off = 32; off > 0; off >>= 1) pw += __shfl_xor(pw, off, 64);
    float sc = 1.0f / fmaxf(sqrtf(pw), 1e-12f);
    float2 r;
    r.x = v.x * sc;
    r.y = v.y * sc;
    *(float2*)&out[(size_t)node * D + lane * 2] = r;
}

// ---------------- launch ----------------

extern "C" void kernel_launch(void* const* d_in, const int* in_sizes, int n_in,
                              void* d_out, int out_size, void* d_ws, size_t ws_size,
                              hipStream_t stream) {
    const float* x  = (const float*)d_in[0];
    const int*   ei = (const int*)d_in[1];
    const float* W1 = (const float*)d_in[2];
    const float* b1 = (const float*)d_in[3];
    const float* W2 = (const float*)d_in[4];
    const float* b2 = (const float*)d_in[5];
    const float* W3 = (const float*)d_in[6];
    const float* b3 = (const float*)d_in[7];
    const float* g1 = (const float*)d_in[8];
    const float* be1 = (const float*)d_in[9];
    const float* g2 = (const float*)d_in[10];
    const float* be2 = (const float*)d_in[11];

    const int N = in_sizes[0] / D;
    const int E = in_sizes[1] / 2;
    const int* src = ei;
    const int* dst = ei + E;
    const float invN = 1.0f / (float)N;

    // workspace carve
    float* Y       = (float*)d_ws;                              // N*D fp32
    unsigned short* hs = (unsigned short*)(Y + (size_t)N * D);  // N*D bf16
    float* dinv    = (float*)(hs + (size_t)N * D);              // N
    float* statsA  = dinv + N;                                  // 1024
    float* statsB  = statsA + 1024;                             // 1024
    unsigned short* wt = (unsigned short*)(statsB + 1024);      // 3*16384 bf16
    int*   cnt     = (int*)(wt + 3 * 16384);                    // N
    int*   row_ptr = cnt + N;                                   // N+1
    int*   cursor  = row_ptr + N + 1;                           // N
    int*   bsum    = cursor + N;                                // 256
    int*   boff    = bsum + 256;                                // 256
    unsigned short* esrc = (unsigned short*)(boff + 256);       // E u16

    const int TB = 256;
    const int gE = (E + TB - 1) / TB;
    const int NB = (N + 255) / 256;
    const int gGemm = (N + 63) / 64;
    dim3 gFill(112, 8);
    dim3 gAgg((N + 15) / 16, 4);
    const int gNode = (N + 3) / 4;

    // W precompute + CSR build
    k_prepw<<<3, TB, 0, stream>>>(W1, W2, W3, wt);
    hipMemsetAsync(cnt, 0, (size_t)N * sizeof(int), stream);
    k_count<<<gE, TB, 0, stream>>>(dst, E, cnt);
    k_scan1<<<NB, TB, 0, stream>>>(cnt, N, bsum);
    k_scan2<<<1, 256, 0, stream>>>(bsum, NB, boff);
    k_scan3<<<NB, TB, 0, stream>>>(cnt, boff, N, E, row_ptr, cursor, dinv);
    k_fill<<<gFill, TB, 0, stream>>>(src, dst, E, cursor, esrc, N);

    // layer 1 (gemm1 zeroes statsA; agg1 accumulates statsA)
    k_gemm<<<gGemm, TB, 0, stream>>>(x, wt, dinv, nullptr, nullptr, nullptr, statsA,
                                     hs, N, invN);
    k_agg<<<gAgg, TB, 0, stream>>>((const unsigned*)hs, row_ptr, esrc, dinv, b1, Y,
                                   statsA, N, 0);

    // layer 2 (gemm2 finalizes BN1 from statsA, zeroes statsB)
    k_gemm<<<gGemm, TB, 0, stream>>>(Y, wt + 16384, dinv, statsA, g1, be1, statsB,
                                     hs, N, invN);
    k_agg<<<gAgg, TB, 0, stream>>>((const unsigned*)hs, row_ptr, esrc, dinv, b2, Y,
                                   statsB, N, 0);

    // layer 3 (gemm3 finalizes BN2 from statsB) + normalize
    k_gemm<<<gGemm, TB, 0, stream>>>(Y, wt + 32768, dinv, statsB, g2, be2, nullptr,
                                     hs, N, invN);
    k_agg<<<gAgg, TB, 0, stream>>>((const unsigned*)hs, row_ptr, esrc, dinv, b3, Y,
                                   nullptr, N, 1);
    k_l2norm<<<gNode, TB, 0, stream>>>(Y, (float*)d_out, N);
}

// Round 10
// 437.536 us; speedup vs baseline: 1.0467x; 1.0467x over previous
//
#include <hip/hip_runtime.h>
#include <hip/hip_bf16.h>

#define D 128

typedef __bf16 bf16x8 __attribute__((ext_vector_type(8)));
typedef float floatx4 __attribute__((ext_vector_type(4)));

// ---------------- CSR build ----------------

__global__ void k_count(const int* __restrict__ dst, int E, int* __restrict__ cnt) {
    int e = blockIdx.x * blockDim.x + threadIdx.x;
    if (e < E) atomicAdd(&cnt[dst[e]], 1);
}

__global__ __launch_bounds__(256) void k_scan1(const int* __restrict__ cnt, int n,
                                               int* __restrict__ bsum) {
    int i = blockIdx.x * 256 + threadIdx.x;
    int x = (i < n) ? cnt[i] : 0;
    #pragma unroll
    for (int off = 32; off > 0; off >>= 1) x += __shfl_xor(x, off, 64);
    __shared__ int ws[4];
    if ((threadIdx.x & 63) == 0) ws[threadIdx.x >> 6] = x;
    __syncthreads();
    if (threadIdx.x == 0) bsum[blockIdx.x] = ws[0] + ws[1] + ws[2] + ws[3];
}

__global__ void k_scan2(const int* __restrict__ bsum, int nb, int* __restrict__ boff) {
    int t = threadIdx.x;
    int lane = t & 63, wid = t >> 6;
    int x = (t < nb) ? bsum[t] : 0;
    int incl = x;
    #pragma unroll
    for (int off = 1; off < 64; off <<= 1) {
        int y = __shfl_up(incl, off, 64);
        if (lane >= off) incl += y;
    }
    __shared__ int ws[4];
    if (lane == 63) ws[wid] = incl;
    __syncthreads();
    int o = 0;
    for (int w = 0; w < wid; w++) o += ws[w];
    if (t < nb) boff[t] = o + incl - x;
}

__global__ __launch_bounds__(256) void k_scan3(const int* __restrict__ cnt,
                                               const int* __restrict__ boff, int n, int E,
                                               int* __restrict__ row_ptr, int* __restrict__ cursor,
                                               float* __restrict__ dinv) {
    int t = threadIdx.x;
    int lane = t & 63, wid = t >> 6;
    int i = blockIdx.x * 256 + t;
    int x = (i < n) ? cnt[i] : 0;
    int incl = x;
    #pragma unroll
    for (int off = 1; off < 64; off <<= 1) {
        int y = __shfl_up(incl, off, 64);
        if (lane >= off) incl += y;
    }
    __shared__ int ws[4];
    if (lane == 63) ws[wid] = incl;
    __syncthreads();
    int o = boff[blockIdx.x];
    for (int w = 0; w < wid; w++) o += ws[w];
    if (i < n) {
        int excl = o + incl - x;
        row_ptr[i] = excl;
        cursor[i] = excl;
        dinv[i] = rsqrtf((float)(x + 1));  // +1 self loop
    }
    if (blockIdx.x == 0 && t == 0) row_ptr[n] = E;
}

// Range-partitioned fill (round-8 proven): blockIdx.y = dst-range (8 ranges).
__global__ __launch_bounds__(256) void k_fill(const int* __restrict__ src,
                                              const int* __restrict__ dst, int E,
                                              int* __restrict__ cursor,
                                              unsigned short* __restrict__ esrc, int n) {
    int rs = (n + 7) >> 3;
    int lo = blockIdx.y * rs, hi = lo + rs;
    int step = gridDim.x * 256;
    for (int e = blockIdx.x * 256 + threadIdx.x; e < E; e += step) {
        int d = dst[e];
        int s = src[e];
        if (d >= lo && d < hi) {
            int p = atomicAdd(&cursor[d], 1);
            esrc[p] = (unsigned short)s;
        }
    }
}

// ---------------- W transpose+bf16 precompute: Wt[n][k] = bf16(W[k][n]) ----------------

__global__ __launch_bounds__(256) void k_prepw(const float* __restrict__ W1,
                                               const float* __restrict__ W2,
                                               const float* __restrict__ W3,
                                               unsigned short* __restrict__ Wt) {
    const float* W = (blockIdx.x == 0) ? W1 : (blockIdx.x == 1) ? W2 : W3;
    unsigned short* o = Wt + blockIdx.x * 16384;
    for (int i = threadIdx.x; i < 16384; i += 256) {
        int k = i >> 7, nn = i & 127;
        __hip_bfloat16 h = __float2bfloat16(W[i]);
        o[nn * 128 + k] = *(unsigned short*)&h;
    }
}

// ---------------- MFMA GEMM (round-7 proven): hs = bf16(relu_bn(X) @ W * dinv) -------
// bn: finalized coefs a[128], b[128] (or nullptr for layer 1).

__global__ __launch_bounds__(256) void k_gemm(
    const float* __restrict__ X, const unsigned short* __restrict__ Wt,
    const float* __restrict__ scale, const float* __restrict__ bn,
    unsigned short* __restrict__ hs, int n) {
    __shared__ unsigned short Wl[128 * 128];
    __shared__ float bnl[256];
    int t = threadIdx.x;
    {
        const uint4* wg = (const uint4*)Wt;
        uint4* wl4 = (uint4*)Wl;
        #pragma unroll
        for (int j = 0; j < 8; j++) {
            int idx = j * 256 + t;
            int nn = idx >> 4, lc = idx & 15;
            wl4[nn * 16 + (lc ^ (nn & 15))] = wg[idx];
        }
    }
    if (bn) bnl[t] = bn[t];
    __syncthreads();

    int l = t & 63, w = t >> 6;
    int lm = l & 15, quad = l >> 4;
    int m = blockIdx.x * 64 + w * 16 + lm;
    int rm = (m < n) ? m : (n - 1);
    const float* xrow = X + (size_t)rm * D;

    floatx4 acc[8];
    #pragma unroll
    for (int nt = 0; nt < 8; nt++) acc[nt] = (floatx4){0.f, 0.f, 0.f, 0.f};

    #pragma unroll
    for (int ks = 0; ks < 4; ks++) {
        int k0 = ks * 32 + quad * 8;
        float4 xa = *(const float4*)(xrow + k0);
        float4 xb = *(const float4*)(xrow + k0 + 4);
        if (bn) {
            float4 a0 = *(const float4*)&bnl[k0];
            float4 a1 = *(const float4*)&bnl[k0 + 4];
            float4 c0 = *(const float4*)&bnl[128 + k0];
            float4 c1 = *(const float4*)&bnl[128 + k0 + 4];
            xa.x = fmaxf(xa.x * a0.x + c0.x, 0.f);
            xa.y = fmaxf(xa.y * a0.y + c0.y, 0.f);
            xa.z = fmaxf(xa.z * a0.z + c0.z, 0.f);
            xa.w = fmaxf(xa.w * a0.w + c0.w, 0.f);
            xb.x = fmaxf(xb.x * a1.x + c1.x, 0.f);
            xb.y = fmaxf(xb.y * a1.y + c1.y, 0.f);
            xb.z = fmaxf(xb.z * a1.z + c1.z, 0.f);
            xb.w = fmaxf(xb.w * a1.w + c1.w, 0.f);
        }
        bf16x8 xf;
        xf[0] = (__bf16)xa.x; xf[1] = (__bf16)xa.y;
        xf[2] = (__bf16)xa.z; xf[3] = (__bf16)xa.w;
        xf[4] = (__bf16)xb.x; xf[5] = (__bf16)xb.y;
        xf[6] = (__bf16)xb.z; xf[7] = (__bf16)xb.w;
        int pc = (ks * 4 + quad) ^ lm;
        #pragma unroll
        for (int nt = 0; nt < 8; nt++) {
            const bf16x8 wf = *(const bf16x8*)&Wl[(nt * 16 + lm) * 128 + pc * 8];
            acc[nt] = __builtin_amdgcn_mfma_f32_16x16x32_bf16(wf, xf, acc[nt], 0, 0, 0);
        }
    }

    float s = scale[rm];
    if (m < n) {
        #pragma unroll
        for (int nt = 0; nt < 8; nt++) {
            __hip_bfloat16 h0 = __float2bfloat16(acc[nt][0] * s);
            __hip_bfloat16 h1 = __float2bfloat16(acc[nt][1] * s);
            __hip_bfloat16 h2 = __float2bfloat16(acc[nt][2] * s);
            __hip_bfloat16 h3 = __float2bfloat16(acc[nt][3] * s);
            uint2 uu;
            uu.x = (unsigned)*(unsigned short*)&h0 | ((unsigned)*(unsigned short*)&h1 << 16);
            uu.y = (unsigned)*(unsigned short*)&h2 | ((unsigned)*(unsigned short*)&h3 << 16);
            *(uint2*)&hs[(size_t)m * D + nt * 16 + quad * 4] = uu;
        }
    }
}

// ---------------- Column-blocked aggregation (round-7 proven shape, u16 esrc) --------
// One node per 16-lane group, 16 nodes/block, 3125 blocks x 4 passes.
// No stats fusion: zero extra atomics (r9 post-mortem: 800k fused-stats atomics
// over 1024 addrs doubled agg time via cross-XCD line ping-pong).

__device__ inline float2 bf2f(unsigned u) {
    union { unsigned i; float f; } lo, hi;
    lo.i = u << 16;
    hi.i = u & 0xffff0000u;
    float2 r; r.x = lo.f; r.y = hi.f; return r;
}

__global__ __launch_bounds__(256) void k_agg(
    const unsigned* __restrict__ hs, const int* __restrict__ row_ptr,
    const unsigned short* __restrict__ esrc, const float* __restrict__ dinv,
    const float* __restrict__ bias, float* __restrict__ out, int n) {
    int grp = threadIdx.x >> 4;
    int node = blockIdx.x * 16 + grp;
    if (node >= n) return;
    int sub = threadIdx.x & 15;
    int p = blockIdx.y;
    int col32 = p * 16 + sub;
    int beg = row_ptr[node], end = row_ptr[node + 1];
    float2 acc = bf2f(hs[(size_t)node * 64 + col32]);   // self loop
    for (int base = beg; base < end; base += 16) {
        int m = end - base;
        if (m > 16) m = 16;
        int eid = (base + sub < end) ? (int)esrc[base + sub] : 0;
        int i = 0;
        for (; i + 8 <= m; i += 8) {
            int u0 = __shfl(eid, i + 0, 16);
            int u1 = __shfl(eid, i + 1, 16);
            int u2 = __shfl(eid, i + 2, 16);
            int u3 = __shfl(eid, i + 3, 16);
            int u4 = __shfl(eid, i + 4, 16);
            int u5 = __shfl(eid, i + 5, 16);
            int u6 = __shfl(eid, i + 6, 16);
            int u7 = __shfl(eid, i + 7, 16);
            unsigned p0 = hs[(size_t)u0 * 64 + col32];
            unsigned p1 = hs[(size_t)u1 * 64 + col32];
            unsigned p2 = hs[(size_t)u2 * 64 + col32];
            unsigned p3 = hs[(size_t)u3 * 64 + col32];
            unsigned p4 = hs[(size_t)u4 * 64 + col32];
            unsigned p5 = hs[(size_t)u5 * 64 + col32];
            unsigned p6 = hs[(size_t)u6 * 64 + col32];
            unsigned p7 = hs[(size_t)u7 * 64 + col32];
            float2 v0 = bf2f(p0), v1 = bf2f(p1), v2 = bf2f(p2), v3 = bf2f(p3);
            float2 v4 = bf2f(p4), v5 = bf2f(p5), v6 = bf2f(p6), v7 = bf2f(p7);
            acc.x += ((v0.x + v1.x) + (v2.x + v3.x)) + ((v4.x + v5.x) + (v6.x + v7.x));
            acc.y += ((v0.y + v1.y) + (v2.y + v3.y)) + ((v4.y + v5.y) + (v6.y + v7.y));
        }
        for (; i + 4 <= m; i += 4) {
            int u0 = __shfl(eid, i + 0, 16);
            int u1 = __shfl(eid, i + 1, 16);
            int u2 = __shfl(eid, i + 2, 16);
            int u3 = __shfl(eid, i + 3, 16);
            unsigned p0 = hs[(size_t)u0 * 64 + col32];
            unsigned p1 = hs[(size_t)u1 * 64 + col32];
            unsigned p2 = hs[(size_t)u2 * 64 + col32];
            unsigned p3 = hs[(size_t)u3 * 64 + col32];
            float2 v0 = bf2f(p0), v1 = bf2f(p1), v2 = bf2f(p2), v3 = bf2f(p3);
            acc.x += (v0.x + v1.x) + (v2.x + v3.x);
            acc.y += (v0.y + v1.y) + (v2.y + v3.y);
        }
        for (; i < m; i++) {
            int u = __shfl(eid, i, 16);
            float2 v = bf2f(hs[(size_t)u * 64 + col32]);
            acc.x += v.x;
            acc.y += v.y;
        }
    }
    float s = dinv[node];
    float2 b = *(const float2*)&bias[col32 * 2];
    float2 r;
    r.x = acc.x * s + b.x;
    r.y = acc.y * s + b.y;
    *(float2*)&out[(size_t)node * D + col32 * 2] = r;
}

// ---------------- BatchNorm (round-7 proven separate kernels) ----------------

__global__ __launch_bounds__(256) void k_bn_stats(const float* __restrict__ y,
                                                  float* __restrict__ stats, int n) {
    int c = threadIdx.x & 127;
    int half = threadIdx.x >> 7;
    float s = 0.f, q = 0.f;
    for (int r = blockIdx.x * 2 + half; r < n; r += gridDim.x * 2) {
        float v = y[(size_t)r * D + c];
        s += v;
        q += v * v;
    }
    __shared__ float ls[256], lq[256];
    ls[threadIdx.x] = s;
    lq[threadIdx.x] = q;
    __syncthreads();
    if (half == 0) {
        s = ls[threadIdx.x] + ls[threadIdx.x + 128];
        q = lq[threadIdx.x] + lq[threadIdx.x + 128];
        atomicAdd(&stats[c], s);
        atomicAdd(&stats[128 + c], q);
    }
}

__global__ void k_bn_finalize(float* __restrict__ stats, const float* __restrict__ gamma,
                              const float* __restrict__ beta, float n) {
    int c = threadIdx.x;  // 128 threads
    float mean = stats[c] / n;
    float var = stats[128 + c] / n - mean * mean;
    float a = gamma[c] * rsqrtf(var + 1e-5f);
    float b = beta[c] - mean * a;
    stats[c] = a;
    stats[128 + c] = b;
}

// ---------------- row L2 normalize ----------------

__global__ __launch_bounds__(256) void k_l2norm(const float* __restrict__ h,
                                                float* __restrict__ out, int n) {
    int node = blockIdx.x * 4 + (threadIdx.x >> 6);
    if (node >= n) return;
    int lane = threadIdx.x & 63;
    float2 v = *(const float2*)&h[(size_t)node * D + lane * 2];
    float pw = v.x * v.x + v.y * v.y;
    #pragma unroll
    for (int off = 32; off > 0; off >>= 1) pw += __shfl_xor(pw, off, 64);
    float sc = 1.0f / fmaxf(sqrtf(pw), 1e-12f);
    float2 r;
    r.x = v.x * sc;
    r.y = v.y * sc;
    *(float2*)&out[(size_t)node * D + lane * 2] = r;
}

// ---------------- launch ----------------

extern "C" void kernel_launch(void* const* d_in, const int* in_sizes, int n_in,
                              void* d_out, int out_size, void* d_ws, size_t ws_size,
                              hipStream_t stream) {
    const float* x  = (const float*)d_in[0];
    const int*   ei = (const int*)d_in[1];
    const float* W1 = (const float*)d_in[2];
    const float* b1 = (const float*)d_in[3];
    const float* W2 = (const float*)d_in[4];
    const float* b2 = (const float*)d_in[5];
    const float* W3 = (const float*)d_in[6];
    const float* b3 = (const float*)d_in[7];
    const float* g1 = (const float*)d_in[8];
    const float* be1 = (const float*)d_in[9];
    const float* g2 = (const float*)d_in[10];
    const float* be2 = (const float*)d_in[11];

    const int N = in_sizes[0] / D;
    const int E = in_sizes[1] / 2;
    const int* src = ei;
    const int* dst = ei + E;

    // workspace carve
    float* Y       = (float*)d_ws;                              // N*D fp32
    unsigned short* hs = (unsigned short*)(Y + (size_t)N * D);  // N*D bf16
    float* dinv    = (float*)(hs + (size_t)N * D);              // N
    float* stats   = dinv + N;                                  // 256
    unsigned short* wt = (unsigned short*)(stats + 256);        // 3*16384 bf16
    int*   cnt     = (int*)(wt + 3 * 16384);                    // N
    int*   row_ptr = cnt + N;                                   // N+1
    int*   cursor  = row_ptr + N + 1;                           // N
    int*   bsum    = cursor + N;                                // 256
    int*   boff    = bsum + 256;                                // 256
    unsigned short* esrc = (unsigned short*)(boff + 256);       // E u16

    const int TB = 256;
    const int gE = (E + TB - 1) / TB;
    const int NB = (N + 255) / 256;
    const int gGemm = (N + 63) / 64;
    dim3 gFill(112, 8);
    dim3 gAgg((N + 15) / 16, 4);
    const int gNode = (N + 3) / 4;

    // W precompute + CSR build
    k_prepw<<<3, TB, 0, stream>>>(W1, W2, W3, wt);
    hipMemsetAsync(cnt, 0, (size_t)N * sizeof(int), stream);
    k_count<<<gE, TB, 0, stream>>>(dst, E, cnt);
    k_scan1<<<NB, TB, 0, stream>>>(cnt, N, bsum);
    k_scan2<<<1, 256, 0, stream>>>(bsum, NB, boff);
    k_scan3<<<NB, TB, 0, stream>>>(cnt, boff, N, E, row_ptr, cursor, dinv);
    k_fill<<<gFill, TB, 0, stream>>>(src, dst, E, cursor, esrc, N);

    // layer 1
    k_gemm<<<gGemm, TB, 0, stream>>>(x, wt, dinv, nullptr, hs, N);
    k_agg<<<gAgg, TB, 0, stream>>>((const unsigned*)hs, row_ptr, esrc, dinv, b1, Y, N);
    hipMemsetAsync(stats, 0, 256 * sizeof(float), stream);
    k_bn_stats<<<256, TB, 0, stream>>>(Y, stats, N);
    k_bn_finalize<<<1, 128, 0, stream>>>(stats, g1, be1, (float)N);

    // layer 2 (BN+ReLU fused into gemm load)
    k_gemm<<<gGemm, TB, 0, stream>>>(Y, wt + 16384, dinv, stats, hs, N);
    k_agg<<<gAgg, TB, 0, stream>>>((const unsigned*)hs, row_ptr, esrc, dinv, b2, Y, N);
    hipMemsetAsync(stats, 0, 256 * sizeof(float), stream);
    k_bn_stats<<<256, TB, 0, stream>>>(Y, stats, N);
    k_bn_finalize<<<1, 128, 0, stream>>>(stats, g2, be2, (float)N);

    // layer 3 + normalize
    k_gemm<<<gGemm, TB, 0, stream>>>(Y, wt + 32768, dinv, stats, hs, N);
    k_agg<<<gAgg, TB, 0, stream>>>((const unsigned*)hs, row_ptr, esrc, dinv, b3, Y, N);
    k_l2norm<<<gNode, TB, 0, stream>>>(Y, (float*)d_out, N);
}